// Round 11
// baseline (123.704 us; speedup 1.0000x reference)
//
#include <hip/hip_runtime.h>

// R21: R20 + dedicated head wave + conflict-free hbuf stride. B=4096, L=256,
// H=32, D=2. 256 WGs x 576 threads (9 waves), 16 batches/WG, 1 WG/CU.
// R20 (65.6us dispatch, matched prediction): 8-wave zero-dup layout, 1 MFMA /
// 0 extract / 1 cell per lane, step ~615cy = 264 issue + ~350 chain. Residual
// inefficiencies attacked here:
//  1. Rotating straggler: the (t-1)&7 head-logit wave added ~25cy to the
//     barrier wall EVERY step. Now wave 8 is a dedicated head wave (short
//     chain, arrives early); compute waves have no branch, no head MFMA.
//  2. hbuf stride 80B -> 88B: 22m mod 32 is all-distinct over m=0..15 ->
//     b16 h-writes conflict-free (was 4 lanes/bank), reads ~2-way (free).
//     Read becomes 2x ds_read_b64 (8B-aligned; b128 needs 16B).
// Everything else = R20: tile T(=wave) row i = gate(i&3) of unit 4T+(i>>2),
// 16 distinct batch cols, bias+Wi*spin in MFMA C-in, combined-rcp cell
// (7 trans), 4-step unroll + dword spin prefetch, cvt_pk h pack, post-loop
// ELU/log-softmax.

typedef __attribute__((ext_vector_type(8))) short bf16x8;
typedef __attribute__((ext_vector_type(4))) short bf16x4;
typedef __attribute__((ext_vector_type(4))) float f32x4;

#define LOG2E 1.4426950408889634f
#define LN2   0.6931471805599453f

__device__ __forceinline__ float fexp2(float x) { return __builtin_amdgcn_exp2f(x); }
__device__ __forceinline__ float flog2(float x) { return __builtin_amdgcn_logf(x); }
__device__ __forceinline__ float frcp(float x)  { return __builtin_amdgcn_rcpf(x); }

__device__ __forceinline__ float fsig(float x)   { return frcp(1.f + fexp2(-LOG2E * x)); }
__device__ __forceinline__ float ftanh_(float x) { return 1.f - 2.f * frcp(fexp2(2.f * LOG2E * x) + 1.f); }
__device__ __forceinline__ float felu(float x)   { return x > 0.f ? x : fexp2(LOG2E * x) - 1.f; }

__device__ __forceinline__ unsigned short f2bf(float f) {   // RNE f32->bf16
    unsigned u = __builtin_bit_cast(unsigned, f);
    u = (u + 0x7FFFu + ((u >> 16) & 1u)) >> 16;
    return (unsigned short)u;
}

__device__ __forceinline__ unsigned cvtpk_bf16(float a, float b) {
    unsigned r;
    asm("v_cvt_pk_bf16_f32 %0, %1, %2" : "=v"(r) : "v"(a), "v"(b));
    return r;   // lo16 = bf16(a), hi16 = bf16(b), RNE
}

constexpr int Bsz = 4096;

__global__ __launch_bounds__(576, 1) void lstm_r21(
    const int*   __restrict__ x,    // [B, 256]
    const float* __restrict__ Wi,   // [2, 128]
    const float* __restrict__ Wh,   // [32, 128]
    const float* __restrict__ bh,   // [128]
    const float* __restrict__ Wo,   // [32, 2]
    const float* __restrict__ bo,   // [2]
    float*       __restrict__ out)  // [B]
{
    const int tid  = threadIdx.x;
    const int w    = tid >> 6;      // wave 0..7 = gate tile, wave 8 = head
    const int lane = tid & 63;
    const int m    = lane & 15;     // MFMA column == batch (16, no dup)
    const int oct  = lane >> 4;
    const int b0   = blockIdx.x * 16;

    __shared__ char   spinT[16][260];     // [batch][t] bytes, padded row
    __shared__ float2 Sbuf[256][16];      // raw logits (S0,S1) per (t,batch)
    __shared__ __align__(16) short hbuf[2][16][44];   // h dbuf, 88B stride:
                                          // 22m mod 32 distinct -> no write
                                          // conflicts; reads 2x b64
    __shared__ float  red[32][16];

    // ---- stage spins: waves 0..7 (512 thr) x 8 bytes ----
    if (w < 8) {
        const int bl = tid >> 5;          // row 0..15
        const int c8 = (tid & 31) * 8;
        const int4* src = reinterpret_cast<const int4*>(x + (b0 + bl) * 256 + c8);
        const int4 v0 = src[0], v1 = src[1];
        const int p0 = (v0.x & 1) | ((v0.y & 1) << 8) | ((v0.z & 1) << 16) | ((v0.w & 1) << 24);
        const int p1 = (v1.x & 1) | ((v1.y & 1) << 8) | ((v1.z & 1) << 16) | ((v1.w & 1) << 24);
        *reinterpret_cast<int*>(&spinT[bl][c8])     = p0;
        *reinterpret_cast<int*>(&spinT[bl][c8 + 4]) = p1;
    }

    // ---- A-frag (compute waves): tile w, row m = gate (m&3) of unit
    // 4w + (m>>2). Head wave: Wo cols in rows 0,1. ----
    const int wc = (w < 8) ? w : 0;       // clamp for in-bounds weight reads
    bf16x8 wfrag;
    {
        const int r = m & 3;
        const float gs = (r == 2) ? 2.f * LOG2E : -LOG2E;
        const int colg = 32 * r + 4 * wc + (m >> 2);
#pragma unroll
        for (int j = 0; j < 8; ++j)
            wfrag[j] = (short)f2bf(gs * Wh[(8 * oct + j) * 128 + colg]);
    }
    bf16x8 wfragO;
#pragma unroll
    for (int j = 0; j < 8; ++j)
        wfragO[j] = (m < 2) ? (short)f2bf(Wo[(8 * oct + j) * 2 + m]) : (short)0;

    // ---- this lane's cell + scaled biases (clamped for head wave) ----
    const int u = 4 * wc + oct;
    float bv0[4], bvd[4];
#pragma unroll
    for (int r = 0; r < 4; ++r) {
        const float gs = (r == 2) ? 2.f * LOG2E : -LOG2E;
        const int c0 = 32 * r + u;
        bv0[r] = gs * (bh[c0] + Wi[c0]);
        bvd[r] = gs * (Wi[128 + c0] - Wi[c0]);
    }
    const float bo0 = bo[0], bo1 = bo[1];

    // ---- peel t=0 (compute waves only: head wave's u aliases wave 0) ----
    float c = 0.f;
    if (w < 8) {
        c = fsig(bh[u]) * ftanh_(bh[64 + u]);
        hbuf[0][m][u] = (short)f2bf(fsig(bh[96 + u]) * ftanh_(c));
    }
    __syncthreads();   // spins + h0 visible

    const int wS = __builtin_amdgcn_readfirstlane(w);
    const f32x4 zero4 = { 0.f, 0.f, 0.f, 0.f };

    auto loadh = [&](const int rb) -> bf16x8 {
        const bf16x4 h0 = *reinterpret_cast<const bf16x4*>(&hbuf[rb][m][8 * oct]);
        const bf16x4 h1 = *reinterpret_cast<const bf16x4*>(&hbuf[rb][m][8 * oct + 4]);
        bf16x8 hf;
#pragma unroll
        for (int j = 0; j < 4; ++j) { hf[j] = h0[j]; hf[4 + j] = h1[j]; }
        return hf;
    };

    // one step; rb/wb compile-time at each call site -> static addresses
    auto step = [&](const int t, const int rb, const int wb, const float spf) {
        if (wS < 8) {
            const bf16x8 hfrag = loadh(rb);
            f32x4 cb;   // bias into MFMA C-in; every slot is this lane's cell
#pragma unroll
            for (int r = 0; r < 4; ++r) cb[r] = fmaf(spf, bvd[r], bv0[r]);
            const f32x4 acc =
                __builtin_amdgcn_mfma_f32_16x16x32_bf16(wfrag, hfrag, cb, 0, 0, 0);
            // cell update (gates = acc directly); combined-rcp form
            const float ei = fexp2(acc[0]), ef = fexp2(acc[1]);
            const float eg = fexp2(acc[2]), eo = fexp2(acc[3]);
            const float P = (1.f + ei) * (1.f + eg);
            const float Q = 1.f + ef;
            const float R = frcp(P * Q);
            c = fmaf(P * R, c, (eg - 1.f) * Q * R);
            const float ec = fexp2(2.f * LOG2E * c);
            const float h  = (ec - 1.f) * frcp((1.f + eo) * (1.f + ec));
            hbuf[wb][m][u] = (short)cvtpk_bf16(h, h);
        } else {
            // head wave: S(t-1) from h_{t-1}; short chain, arrives early
            const bf16x8 hfrag = loadh(rb);
            const f32x4 aO =
                __builtin_amdgcn_mfma_f32_16x16x32_bf16(wfragO, hfrag, zero4, 0, 0, 0);
            if (oct == 0) Sbuf[t - 1][m] = make_float2(aO[0], aO[1]);
        }
        __syncthreads();   // h_t visible to all waves
    };

    // 4-step unroll; spins for steps (tb..tb+3) = bytes (tb-1..tb+2), one
    // aligned dword, prefetched a group ahead (tb-1 % 4 == 0 -> aligned).
    unsigned sp4 = *reinterpret_cast<const unsigned*>(&spinT[m][0]);
    for (int tb = 1; tb < 253; tb += 4) {
        const unsigned sp4n =
            *reinterpret_cast<const unsigned*>(&spinT[m][tb + 3]);
        step(tb,     0, 1, (float)(sp4 & 0xFFu));
        step(tb + 1, 1, 0, (float)((sp4 >> 8) & 0xFFu));
        step(tb + 2, 0, 1, (float)((sp4 >> 16) & 0xFFu));
        step(tb + 3, 1, 0, (float)(sp4 >> 24));
        sp4 = sp4n;
    }
    // tail steps 253..255 use spin bytes 252..254
    step(253, 0, 1, (float)(sp4 & 0xFFu));
    step(254, 1, 0, (float)((sp4 >> 8) & 0xFFu));
    step(255, 0, 1, (float)((sp4 >> 16) & 0xFFu));

    // ---- tail: head logits of step 255 (h_255 in hbuf[1]) by head wave ----
    if (wS == 8) {
        const bf16x8 hfrag = loadh(1);
        const f32x4 aO =
            __builtin_amdgcn_mfma_f32_16x16x32_bf16(wfragO, hfrag, zero4, 0, 0, 0);
        if (oct == 0) Sbuf[255][m] = make_float2(aO[0], aO[1]);
    }
    __syncthreads();

    // ---- post phase: ELU + log-softmax + sum over t, 32 time-chunks ----
    if (tid < 512) {
        float lp = 0.f;
        const int bpost = tid & 15;     // batch
        const int tc    = tid >> 4;     // time chunk 0..31
#pragma unroll
        for (int i = 0; i < 8; ++i) {
            const int t = tc * 8 + i;
            const float2 sv = Sbuf[t][bpost];
            const int sp = spinT[bpost][t];
            const float o0 = felu(sv.x + bo0);
            const float o1 = felu(sv.y + bo1);
            const float mx = fmaxf(o0, o1), mn = fminf(o0, o1);
            const float lse = mx + LN2 * flog2(1.f + fexp2(LOG2E * (mn - mx)));
            lp += (sp ? o1 : o0) - lse;
        }
        red[tc][bpost] = lp;
    }
    __syncthreads();
    if (tid < 16) {
        float s = 0.f;
#pragma unroll
        for (int tc2 = 0; tc2 < 32; ++tc2) s += red[tc2][tid];
        out[b0 + tid] = 0.5f * s;
    }
}

extern "C" void kernel_launch(void* const* d_in, const int* in_sizes, int n_in,
                              void* d_out, int out_size, void* d_ws, size_t ws_size,
                              hipStream_t stream) {
    const int*   x  = (const int*)d_in[0];
    const float* Wi = (const float*)d_in[1];
    const float* Wh = (const float*)d_in[2];
    const float* bh = (const float*)d_in[3];
    const float* Wo = (const float*)d_in[4];
    const float* bo = (const float*)d_in[5];
    float* out = (float*)d_out;

    // 256 WGs = 1 per CU; 8 compute waves (2/SIMD) + 1 early-arriving head
    // wave. Minimum-issue zero-dup layout, conflict-free 88B hbuf stride.
    lstm_r21<<<dim3(Bsz / 16), dim3(576), 0, stream>>>(x, Wi, Wh, bh, Wo, bo, out);
}